// Round 4
// baseline (9928.517 us; speedup 1.0000x reference)
//
#include <hip/hip_runtime.h>
#include <hip/hip_bf16.h>
#include <cstdint>
#include <cstddef>

#define B_    32
#define S_    512
#define IN_   256
#define HID_  512
#define NGATE 1024
#define OUT_  256
#define NWG   32         // workgroups (each owns 16 cols of r/u/cand, both dirs)

typedef float f32x4 __attribute__((ext_vector_type(4)));
typedef short bf16x8 __attribute__((ext_vector_type(8)));
typedef unsigned long long ull;

__device__ inline unsigned short f2bf(float f) {
  return __builtin_bit_cast(unsigned short, __float2bfloat16(f));
}
__device__ inline float bf2f(unsigned short u) {
  union { float f; unsigned int i; } v; v.i = ((unsigned int)u) << 16; return v.f;
}

// write-through stores: bypass L1/L2 dirty state, land at coherent point (IF$).
__device__ inline void store_short_wt(unsigned short* p, unsigned short val) {
  unsigned int v = val;
  asm volatile("global_store_short %0, %1, off sc0 sc1" :: "v"(p), "v"(v) : "memory");
}
__device__ inline void store_dword_wt(unsigned* p, unsigned val) {
  asm volatile("global_store_dword %0, %1, off sc0 sc1" :: "v"(p), "v"(val) : "memory");
}
// coherent loads (cross-XCD visible) with compiler-tracked waitcnt
__device__ inline bf16x8 load_frag_coh(const unsigned short* p) {
  union { ull u[2]; bf16x8 v; } f;
  f.u[0] = __hip_atomic_load((const ull*)p,       __ATOMIC_RELAXED, __HIP_MEMORY_SCOPE_AGENT);
  f.u[1] = __hip_atomic_load((const ull*)(p + 4), __ATOMIC_RELAXED, __HIP_MEMORY_SCOPE_AGENT);
  return f.v;
}
__device__ inline float load_bf_coh(const unsigned short* p) {
  return bf2f(__hip_atomic_load(p, __ATOMIC_RELAXED, __HIP_MEMORY_SCOPE_AGENT));
}

// ---------------------------------------------------------------- prep ----
__global__ void prep_kernel(const float* __restrict__ x,
                            const float* __restrict__ fcw,
                            unsigned short* __restrict__ Xbf,
                            unsigned short* __restrict__ HFW,
                            unsigned short* __restrict__ HBW,
                            float* __restrict__ pool,
                            unsigned* __restrict__ flags,
                            unsigned short* __restrict__ fcwf)
{
  const int nthreads = gridDim.x * blockDim.x;
  const int gtid = blockIdx.x * blockDim.x + threadIdx.x;

  // x [B,S,IN] -> Xbf [S][B][IN] bf16
  for (int i = gtid; i < S_*B_*IN_; i += nthreads) {
    int c = i & (IN_-1);
    int rem = i >> 8;
    int b = rem & (B_-1);
    int s = rem >> 5;
    Xbf[((size_t)s*B_ + b)*IN_ + c] = f2bf(x[((size_t)b*S_ + s)*IN_ + c]);
  }
  // HFW[0] = 0 (h_{-1}), HBW[S-1] = 0 (hb_S)
  for (int i = gtid; i < B_*HID_; i += nthreads) {
    HFW[i] = 0;
    HBW[(size_t)(S_-1)*B_*HID_ + i] = 0;
  }
  for (int i = gtid; i < B_*HID_; i += nthreads) pool[i] = 0.f;
  for (int i = gtid; i < 128;     i += nthreads) flags[i] = 0u;
  // fc_w [1280][512] -> fragment order [kc=40][nt=32][lane=64][8]
  for (int i = gtid; i < 40*32*64*8; i += nthreads) {
    int j     = i & 7;
    int lane_ = (i >> 3) & 63;
    int nt    = (i >> 9) & 31;
    int kc    = i >> 14;
    int k = kc*32 + (lane_ >> 4)*8 + j;
    int n = nt*16 + (lane_ & 15);
    fcwf[i] = f2bf(fcw[(size_t)k*HID_ + n]);
  }
}

// ------------------------------------------------------------- pregemm ----
// GX[dir][t*32+b][1024] = x_{t,b} @ Wg[0:256,:] + bg   (bf16)
// GC[dir][t*32+b][512]  = x_{t,b} @ Wc[0:256,:] + bc   (bf16)
__global__ __launch_bounds__(256, 1)
void pregemm_kernel(const unsigned short* __restrict__ Xbf,
                    const float* __restrict__ Wg_fw, const float* __restrict__ bg_fw,
                    const float* __restrict__ Wc_fw, const float* __restrict__ bc_fw,
                    const float* __restrict__ Wg_bw, const float* __restrict__ bg_bw,
                    const float* __restrict__ Wc_bw, const float* __restrict__ bc_bw,
                    unsigned short* __restrict__ GX, unsigned short* __restrict__ GC)
{
  __shared__ unsigned short bsm[4*8*64*8];   // 32KB [nt4][kk8][lane][8]
  const int id  = blockIdx.x;                // 0..12287
  const int dir = id >= 6144;
  const int r0  = id - dir*6144;
  const int mtile = r0 / 24;
  const int sec   = r0 % 24;
  const bool isG  = sec < 16;
  const float* W    = dir ? (isG ? Wg_bw : Wc_bw) : (isG ? Wg_fw : Wc_fw);
  const float* bias = dir ? (isG ? bg_bw : bc_bw) : (isG ? bg_fw : bc_fw);
  const int N     = isG ? NGATE : HID_;
  const int nbase = (isG ? sec : sec - 16) * 64;
  unsigned short* out = isG ? (GX + (size_t)dir*16384*NGATE)
                            : (GC + (size_t)dir*16384*HID_);
  const int m0 = mtile * 64;
  const int tid = threadIdx.x, wave = tid >> 6, lane = tid & 63;
  const int quad = lane >> 4, l16 = lane & 15;

  for (int idx = tid; idx < 4*8*64; idx += 256) {
    int lane_ = idx & 63, kk = (idx >> 6) & 7, nt = idx >> 9;
    int n  = nbase + nt*16 + (lane_ & 15);
    int kb = kk*32 + (lane_ >> 4)*8;
    #pragma unroll
    for (int j = 0; j < 8; ++j)
      bsm[((nt*8 + kk)*64 + lane_)*8 + j] = f2bf(W[(size_t)(kb + j)*N + n]);
  }
  __syncthreads();

  f32x4 acc[4];
  #pragma unroll
  for (int nt = 0; nt < 4; ++nt) acc[nt] = (f32x4){0.f,0.f,0.f,0.f};
  #pragma unroll
  for (int kk = 0; kk < 8; ++kk) {
    bf16x8 af = *(const bf16x8*)(Xbf + (size_t)(m0 + wave*16 + l16)*IN_ + quad*8 + kk*32);
    #pragma unroll
    for (int nt = 0; nt < 4; ++nt) {
      bf16x8 bv = *(const bf16x8*)(&bsm[((nt*8 + kk)*64 + lane)*8]);
      acc[nt] = __builtin_amdgcn_mfma_f32_16x16x32_bf16(af, bv, acc[nt], 0, 0, 0);
    }
  }
  #pragma unroll
  for (int nt = 0; nt < 4; ++nt)
    #pragma unroll
    for (int r = 0; r < 4; ++r) {
      int row = m0 + wave*16 + quad*4 + r;
      int col = nbase + nt*16 + l16;
      out[(size_t)row*N + col] = f2bf(acc[nt][r] + bias[col]);
    }
}

// ----------------------------------------------------------- barrier ----
__device__ inline void post_flag(unsigned* f, int g, unsigned v) {
  __syncthreads();                       // drains this WG's wt data stores
  if (threadIdx.x == 0) store_dword_wt(f + g, v);
}
__device__ inline void wait_flags(unsigned* f, unsigned target) {
  if (threadIdx.x < 64) {                // wave 0 polls
    for (;;) {
      unsigned v = __hip_atomic_load(f + (threadIdx.x & 31),
                                     __ATOMIC_RELAXED, __HIP_MEMORY_SCOPE_AGENT);
      if (!__any((int)(v < target))) break;
      __builtin_amdgcn_s_sleep(2);
    }
  }
  __syncthreads();                       // release other waves
}

// --------------------------------------------------------------- gru ----
// 32 WGs x 256 threads.  WG g owns cols [g*16, g*16+16) of r, u, cand for
// BOTH directions.  Pipeline per step:
//   fw.A -> post -> bw.A -> post -> wait(fwA) -> fw.B -> post -> wait(bwA)
//   -> bw.B -> post ; next iter starts with wait(fwB)/wait(bwB).
// Each wait is preceded by an independent compute block (latency hiding).
__global__ __launch_bounds__(256, 1)
void gru_kernel(const float* __restrict__ Wg_fw, const float* __restrict__ Wc_fw,
                const float* __restrict__ Wg_bw, const float* __restrict__ Wc_bw,
                const unsigned short* __restrict__ GX, const unsigned short* __restrict__ GC,
                unsigned short* __restrict__ HFW, unsigned short* __restrict__ HBW,
                unsigned short* __restrict__ rhbuf, unsigned* __restrict__ flags)
{
  __shared__ unsigned short wg_lds[2][2][16][64*8];  // 64KB [dir][nt][kk][lane*8]
  __shared__ unsigned short wc_lds[2][16][64*8];     // 32KB [dir][kk][lane*8]
  __shared__ float u_lds[2][B_][16];                 // 4KB
  __shared__ float red_lds[2][64*4];                 // 2KB
  const int g   = blockIdx.x;
  const int tid = threadIdx.x;
  const int wave = tid >> 6, lane = tid & 63;
  const int quad = lane >> 4, l16 = lane & 15;

  // ---- stage weight h-rows (256..767) into LDS as B-fragments ----
  for (int idx = tid; idx < 2*2*16*64; idx += 256) {
    int lane_ = idx & 63, kk = (idx >> 6) & 15, nt = (idx >> 10) & 1, dir = idx >> 11;
    const float* W = dir ? Wg_bw : Wg_fw;
    int n  = (nt ? HID_ : 0) + g*16 + (lane_ & 15);
    int kb = IN_ + kk*32 + (lane_ >> 4)*8;
    #pragma unroll
    for (int j = 0; j < 8; ++j)
      wg_lds[dir][nt][kk][lane_*8 + j] = f2bf(W[(size_t)(kb + j)*NGATE + n]);
  }
  for (int idx = tid; idx < 2*16*64; idx += 256) {
    int lane_ = idx & 63, kk = (idx >> 6) & 15, dir = idx >> 10;
    const float* W = dir ? Wc_bw : Wc_fw;
    int n  = g*16 + (lane_ & 15);
    int kb = IN_ + kk*32 + (lane_ >> 4)*8;
    #pragma unroll
    for (int j = 0; j < 8; ++j)
      wc_lds[dir][kk][lane_*8 + j] = f2bf(W[(size_t)(kb + j)*HID_ + n]);
  }
  __syncthreads();

  unsigned* fA = flags;        // fw phase A
  unsigned* fB = flags + 32;   // fw phase B
  unsigned* gA = flags + 64;   // bw phase A
  unsigned* gB = flags + 96;   // bw phase B

  // phase A: gates = sigmoid(h_prev @ Wg_h + GX[t]); r*h -> rh (wt), u -> LDS
  auto phaseA = [&](int dir, int t) {
    const int nt = wave & 1, mt = wave >> 1;
    unsigned short* H = dir ? HBW : HFW;
    unsigned short* rh = rhbuf + dir*(B_*HID_);
    const unsigned short* hrow = H + ((size_t)t*B_ + mt*16 + l16)*HID_ + quad*8;
    bf16x8 ah[16];
    #pragma unroll
    for (int kk = 0; kk < 16; ++kk) ah[kk] = load_frag_coh(hrow + kk*32);
    const int b0 = mt*16 + quad*4;
    const int col_g = (nt ? HID_ : 0) + g*16 + l16;
    const unsigned short* gx = GX + ((size_t)dir*16384 + (size_t)t*B_)*NGATE;
    float gxv[4];
    #pragma unroll
    for (int r = 0; r < 4; ++r) gxv[r] = bf2f(gx[(size_t)(b0 + r)*NGATE + col_g]);
    float hp[4];
    if (nt == 0) {
      #pragma unroll
      for (int r = 0; r < 4; ++r)
        hp[r] = load_bf_coh(&H[((size_t)t*B_ + b0 + r)*HID_ + g*16 + l16]);
    }
    f32x4 a0 = {0.f,0.f,0.f,0.f}, a1 = {0.f,0.f,0.f,0.f};
    #pragma unroll
    for (int kk = 0; kk < 16; ++kk) {
      bf16x8 bv = *(const bf16x8*)(&wg_lds[dir][nt][kk][lane*8]);
      if (kk & 1) a1 = __builtin_amdgcn_mfma_f32_16x16x32_bf16(ah[kk], bv, a1, 0, 0, 0);
      else        a0 = __builtin_amdgcn_mfma_f32_16x16x32_bf16(ah[kk], bv, a0, 0, 0, 0);
    }
    f32x4 acc = a0 + a1;
    if (nt == 0) {
      #pragma unroll
      for (int r = 0; r < 4; ++r) {
        float rv = 1.f / (1.f + __expf(-(acc[r] + gxv[r])));
        store_short_wt(&rh[(size_t)(b0 + r)*HID_ + g*16 + l16], f2bf(rv * hp[r]));
      }
    } else {
      #pragma unroll
      for (int r = 0; r < 4; ++r)
        u_lds[dir][b0 + r][l16] = 1.f / (1.f + __expf(-(acc[r] + gxv[r])));
    }
  };

  // phase B: c = tanh(rh @ Wc_h + GC[t]); h_new -> H[to] (wt)
  auto phaseB = [&](int dir, int t, int to) {
    const int mt = wave & 1, kh = wave >> 1;
    unsigned short* H = dir ? HBW : HFW;
    const unsigned short* rh = rhbuf + dir*(B_*HID_);
    const unsigned short* rr = rh + (size_t)(mt*16 + l16)*HID_ + kh*256 + quad*8;
    bf16x8 rf[8];
    #pragma unroll
    for (int kk = 0; kk < 8; ++kk) rf[kk] = load_frag_coh(rr + kk*32);
    f32x4 a0 = {0.f,0.f,0.f,0.f}, a1 = {0.f,0.f,0.f,0.f};
    #pragma unroll
    for (int kk = 0; kk < 8; ++kk) {
      bf16x8 bv = *(const bf16x8*)(&wc_lds[dir][kh*8 + kk][lane*8]);
      if (kk & 1) a1 = __builtin_amdgcn_mfma_f32_16x16x32_bf16(rf[kk], bv, a1, 0, 0, 0);
      else        a0 = __builtin_amdgcn_mfma_f32_16x16x32_bf16(rf[kk], bv, a0, 0, 0, 0);
    }
    f32x4 acc = a0 + a1;
    if (kh == 1) {
      #pragma unroll
      for (int r = 0; r < 4; ++r) red_lds[mt][lane*4 + r] = acc[r];
    }
    __syncthreads();
    if (kh == 0) {
      const int b0 = mt*16 + quad*4;
      const int col = g*16 + l16;
      #pragma unroll
      for (int r = 0; r < 4; ++r) {
        float sum = acc[r] + red_lds[mt][lane*4 + r];
        float gcv = bf2f(GC[((size_t)dir*16384 + (size_t)t*B_ + b0 + r)*HID_ + col]);
        float hp  = load_bf_coh(&H[((size_t)t*B_ + b0 + r)*HID_ + col]);
        float c   = tanhf(sum + gcv);
        float u   = u_lds[dir][b0 + r][l16];
        float hn  = u * hp + (1.f - u)*c;
        if (to >= 0 && to < S_)
          store_short_wt(&H[((size_t)to*B_ + b0 + r)*HID_ + col], f2bf(hn));
      }
    }
  };

  for (int si = 0; si < S_; ++si) {
    const int tb = S_ - 1 - si;
    wait_flags(fB, (unsigned)si);
    phaseA(0, si);
    post_flag(fA, g, (unsigned)(si + 1));
    wait_flags(gB, (unsigned)si);
    phaseA(1, tb);
    post_flag(gA, g, (unsigned)(si + 1));
    wait_flags(fA, (unsigned)(si + 1));
    phaseB(0, si, si + 1);
    post_flag(fB, g, (unsigned)(si + 1));
    wait_flags(gA, (unsigned)(si + 1));
    phaseB(1, tb, tb - 1);
    post_flag(gB, g, (unsigned)(si + 1));
  }
}

// ---------------------------------------------------------------- fc ----
// last[b][t] = [HFW[t] | Xbf[t] | HBW[t]]; pool = max_t relu(last@fcw+fcb)
__global__ __launch_bounds__(512, 1)
void fc_kernel(const unsigned short* __restrict__ HFW, const unsigned short* __restrict__ HBW,
               const unsigned short* __restrict__ Xbf,
               const unsigned short* __restrict__ fcwf, const float* __restrict__ fcb,
               float* __restrict__ pool)
{
  __shared__ unsigned short bsm[32*512];   // 32KB weight chunk (frag order)
  __shared__ float red[8*512];             // 16KB cross-wave max reduce
  const int wg = blockIdx.x;               // 128 WGs: b = wg/4, t-quarter = wg%4
  const int b  = wg >> 2;
  const int tid = threadIdx.x, wave = tid >> 6, lane = tid & 63;
  const int quad = lane >> 4, l16 = lane & 15;
  const int t = (wg & 3)*128 + wave*16 + l16;  // A-operand row = t

  f32x4 acc[32];
  #pragma unroll
  for (int nt = 0; nt < 32; ++nt) acc[nt] = (f32x4){0.f,0.f,0.f,0.f};

  for (int kc = 0; kc < 40; ++kc) {
    __syncthreads();
    const uint4* src = (const uint4*)(fcwf + (size_t)kc*32*512);
    uint4* dst = (uint4*)bsm;
    #pragma unroll
    for (int r = 0; r < 4; ++r) dst[tid + r*512] = src[tid + r*512];
    __syncthreads();

    const unsigned short* ap;
    if (kc < 16)      ap = HFW + ((size_t)t*B_ + b)*HID_ + kc*32 + quad*8;        // c_left
    else if (kc < 24) ap = Xbf + ((size_t)t*B_ + b)*IN_ + (kc - 16)*32 + quad*8;  // x
    else              ap = HBW + ((size_t)t*B_ + b)*HID_ + (kc - 24)*32 + quad*8; // c_right
    const bf16x8 af = *(const bf16x8*)ap;
    #pragma unroll
    for (int nt = 0; nt < 32; ++nt) {
      bf16x8 bfv = *(const bf16x8*)(&bsm[(nt*64 + lane)*8]);
      acc[nt] = __builtin_amdgcn_mfma_f32_16x16x32_bf16(af, bfv, acc[nt], 0, 0, 0);
    }
  }
  #pragma unroll
  for (int nt = 0; nt < 32; ++nt) {
    float m = fmaxf(fmaxf(acc[nt][0], acc[nt][1]), fmaxf(acc[nt][2], acc[nt][3]));
    m = fmaxf(m, __shfl_xor(m, 16, 64));
    m = fmaxf(m, __shfl_xor(m, 32, 64));
    if (quad == 0) red[wave*512 + nt*16 + l16] = m;
  }
  __syncthreads();
  {
    float m = red[tid];
    #pragma unroll
    for (int w = 1; w < 8; ++w) m = fmaxf(m, red[w*512 + tid]);
    m = fmaxf(m + fcb[tid], 0.f);
    atomicMax((int*)&pool[(size_t)b*HID_ + tid], __float_as_int(m));
  }
}

// --------------------------------------------------------------- mlp ----
__global__ void mlp_kernel(const float* __restrict__ pool, const float* __restrict__ w,
                           const float* __restrict__ bias, float* __restrict__ out)
{
  __shared__ float p[HID_];
  const int b = blockIdx.x, tid = threadIdx.x;  // 256 threads
  p[tid]       = pool[(size_t)b*HID_ + tid];
  p[tid + 256] = pool[(size_t)b*HID_ + 256 + tid];
  __syncthreads();
  float acc = bias[tid];
  for (int k = 0; k < HID_; ++k) acc += p[k] * w[(size_t)k*OUT_ + tid];
  out[(size_t)b*OUT_ + tid] = acc;
}

// ------------------------------------------------------------ launch ----
extern "C" void kernel_launch(void* const* d_in, const int* in_sizes, int n_in,
                              void* d_out, int out_size, void* d_ws, size_t ws_size,
                              hipStream_t stream)
{
  const float* x    = (const float*)d_in[0];
  const float* fwWg = (const float*)d_in[1];
  const float* fwbg = (const float*)d_in[2];
  const float* fwWc = (const float*)d_in[3];
  const float* fwbc = (const float*)d_in[4];
  const float* bwWg = (const float*)d_in[5];
  const float* bwbg = (const float*)d_in[6];
  const float* bwWc = (const float*)d_in[7];
  const float* bwbc = (const float*)d_in[8];
  const float* fcw  = (const float*)d_in[9];
  const float* fcb  = (const float*)d_in[10];
  const float* mlpw = (const float*)d_in[11];
  const float* mlpb = (const float*)d_in[12];
  float* out = (float*)d_out;

  char* p = (char*)d_ws;
  auto take = [&](size_t bytes) { char* r = p; p += (bytes + 255) & ~size_t(255); return r; };
  unsigned short* Xbf  = (unsigned short*)take((size_t)S_*B_*IN_*2);          // 8MB
  unsigned short* HFW  = (unsigned short*)take((size_t)S_*B_*HID_*2);         // 16MB
  unsigned short* HBW  = (unsigned short*)take((size_t)S_*B_*HID_*2);         // 16MB
  unsigned short* GX   = (unsigned short*)take((size_t)2*S_*B_*NGATE*2);      // 64MB
  unsigned short* GC   = (unsigned short*)take((size_t)2*S_*B_*HID_*2);       // 32MB
  unsigned short* rh   = (unsigned short*)take((size_t)2*B_*HID_*2);
  unsigned short* fcwf = (unsigned short*)take((size_t)40*32*64*8*2);         // 1.25MB
  float*          pool = (float*)take((size_t)B_*HID_*4);
  unsigned*       flags= (unsigned*)take(512);

  prep_kernel<<<2048, 256, 0, stream>>>(x, fcw, Xbf, HFW, HBW, pool, flags, fcwf);
  pregemm_kernel<<<12288, 256, 0, stream>>>(Xbf, fwWg, fwbg, fwWc, fwbc,
                                            bwWg, bwbg, bwWc, bwbc, GX, GC);
  gru_kernel<<<NWG, 256, 0, stream>>>(fwWg, fwWc, bwWg, bwWc,
                                      GX, GC, HFW, HBW, rh, flags);
  fc_kernel<<<128, 512, 0, stream>>>(HFW, HBW, Xbf, fcwf, fcb, pool);
  mlp_kernel<<<32, 256, 0, stream>>>(pool, mlpw, mlpb, out);
}

// Round 8
// 4965.488 us; speedup vs baseline: 1.9995x; 1.9995x over previous
//
#include <hip/hip_runtime.h>
#include <hip/hip_bf16.h>
#include <cstdint>
#include <cstddef>

#define B_    32
#define S_    512
#define IN_   256
#define HID_  512
#define NGATE 1024
#define OUT_  256
#define NWGD  16         // worker WGs per direction (each owns 32 r/u/cand cols)

typedef float f32x4 __attribute__((ext_vector_type(4)));
typedef short bf16x8 __attribute__((ext_vector_type(8)));
typedef unsigned long long ull;

__device__ inline unsigned short f2bf(float f) {
  return __builtin_bit_cast(unsigned short, __float2bfloat16(f));
}
__device__ inline float bf2f(unsigned short u) {
  union { float f; unsigned int i; } v; v.i = ((unsigned int)u) << 16; return v.f;
}

// write-through store: bypasses L1/L2 dirty state, lands at IF$ (device
// coherent point).  R1/R2/R3-verified.
__device__ inline void store_dword_wt(unsigned* p, unsigned val) {
  asm volatile("global_store_dword %0, %1, off sc0 sc1" :: "v"(p), "v"(val) : "memory");
}
// coherent 8B load (cross-XCD visible, compiler-tracked waitcnt). R2/R3-verified.
__device__ inline ull load_u64_coh(const ull* p) {
  return __hip_atomic_load(p, __ATOMIC_RELAXED, __HIP_MEMORY_SCOPE_AGENT);
}

// ---------------------------------------------------------------- prep ----
__global__ void prep_kernel(const float* __restrict__ x,
                            const float* __restrict__ fcw,
                            unsigned short* __restrict__ Xbf,
                            unsigned short* __restrict__ HFW,
                            unsigned short* __restrict__ HBW,
                            float* __restrict__ pool,
                            unsigned* __restrict__ sync,
                            unsigned short* __restrict__ fcwf)
{
  const int nthreads = gridDim.x * blockDim.x;
  const int gtid = blockIdx.x * blockDim.x + threadIdx.x;

  // x [B,S,IN] -> Xbf [S][B][IN] bf16
  for (int i = gtid; i < S_*B_*IN_; i += nthreads) {
    int c = i & (IN_-1);
    int rem = i >> 8;
    int b = rem & (B_-1);
    int s = rem >> 5;
    Xbf[((size_t)s*B_ + b)*IN_ + c] = f2bf(x[((size_t)b*S_ + s)*IN_ + c]);
  }
  // HFW[0] = 0 (h_{-1}), HBW[S-1] = 0 (hb_S)
  for (int i = gtid; i < B_*HID_; i += nthreads) {
    HFW[i] = 0;
    HBW[(size_t)(S_-1)*B_*HID_ + i] = 0;
  }
  for (int i = gtid; i < B_*HID_; i += nthreads) pool[i] = 0.f;
  for (int i = gtid; i < 2048;    i += nthreads) sync[i] = 0u;
  // fc_w [1280][512] -> fragment order [kc=40][nt=32][lane=64][8]
  for (int i = gtid; i < 40*32*64*8; i += nthreads) {
    int j     = i & 7;
    int lane_ = (i >> 3) & 63;
    int nt    = (i >> 9) & 31;
    int kc    = i >> 14;
    int k = kc*32 + (lane_ >> 4)*8 + j;
    int n = nt*16 + (lane_ & 15);
    fcwf[i] = f2bf(fcw[(size_t)k*HID_ + n]);
  }
}

// ------------------------------------------------------------- pregemm ----
// GX[dir][t*32+b][1024] = x_{t,b} @ Wg[0:256,:] + bg   (bf16)  [R3-verified]
// GC[dir][t*32+b][512]  = x_{t,b} @ Wc[0:256,:] + bc   (bf16)
__global__ __launch_bounds__(256, 1)
void pregemm_kernel(const unsigned short* __restrict__ Xbf,
                    const float* __restrict__ Wg_fw, const float* __restrict__ bg_fw,
                    const float* __restrict__ Wc_fw, const float* __restrict__ bc_fw,
                    const float* __restrict__ Wg_bw, const float* __restrict__ bg_bw,
                    const float* __restrict__ Wc_bw, const float* __restrict__ bc_bw,
                    unsigned short* __restrict__ GX, unsigned short* __restrict__ GC)
{
  __shared__ unsigned short bsm[4*8*64*8];   // 32KB [nt4][kk8][lane][8]
  const int id  = blockIdx.x;                // 0..12287
  const int dir = id >= 6144;
  const int r0  = id - dir*6144;
  const int mtile = r0 / 24;
  const int sec   = r0 % 24;
  const bool isG  = sec < 16;
  const float* W    = dir ? (isG ? Wg_bw : Wc_bw) : (isG ? Wg_fw : Wc_fw);
  const float* bias = dir ? (isG ? bg_bw : bc_bw) : (isG ? bg_fw : bc_fw);
  const int N     = isG ? NGATE : HID_;
  const int nbase = (isG ? sec : sec - 16) * 64;
  unsigned short* out = isG ? (GX + (size_t)dir*16384*NGATE)
                            : (GC + (size_t)dir*16384*HID_);
  const int m0 = mtile * 64;
  const int tid = threadIdx.x, wave = tid >> 6, lane = tid & 63;
  const int quad = lane >> 4, l16 = lane & 15;

  for (int idx = tid; idx < 4*8*64; idx += 256) {
    int lane_ = idx & 63, kk = (idx >> 6) & 7, nt = idx >> 9;
    int n  = nbase + nt*16 + (lane_ & 15);
    int kb = kk*32 + (lane_ >> 4)*8;
    #pragma unroll
    for (int j = 0; j < 8; ++j)
      bsm[((nt*8 + kk)*64 + lane_)*8 + j] = f2bf(W[(size_t)(kb + j)*N + n]);
  }
  __syncthreads();

  f32x4 acc[4];
  #pragma unroll
  for (int nt = 0; nt < 4; ++nt) acc[nt] = (f32x4){0.f,0.f,0.f,0.f};
  #pragma unroll
  for (int kk = 0; kk < 8; ++kk) {
    bf16x8 af = *(const bf16x8*)(Xbf + (size_t)(m0 + wave*16 + l16)*IN_ + quad*8 + kk*32);
    #pragma unroll
    for (int nt = 0; nt < 4; ++nt) {
      bf16x8 bv = *(const bf16x8*)(&bsm[((nt*8 + kk)*64 + lane)*8]);
      acc[nt] = __builtin_amdgcn_mfma_f32_16x16x32_bf16(af, bv, acc[nt], 0, 0, 0);
    }
  }
  #pragma unroll
  for (int nt = 0; nt < 4; ++nt)
    #pragma unroll
    for (int r = 0; r < 4; ++r) {
      int row = m0 + wave*16 + quad*4 + r;
      int col = nbase + nt*16 + l16;
      out[(size_t)row*N + col] = f2bf(acc[nt][r] + bias[col]);
    }
}

// ----------------------------------------------------------- barrier ----
// Each flag on its own 64B line (post contention-free); polled with
// agent-relaxed atomic loads (R2/R3-verified).  __syncthreads inside
// post_flag drains this WG's wt data stores before the flag post.
__device__ inline void post_flag(unsigned* base, int g, unsigned v) {
  __syncthreads();
  if (threadIdx.x == 0) store_dword_wt(base + g*16, v);
}
__device__ inline void wait_flags(unsigned* base, unsigned target) {
  if (threadIdx.x < 64) {
    const unsigned* p = base + (threadIdx.x & (NWGD-1))*16;
    for (;;) {
      unsigned v = __hip_atomic_load(p, __ATOMIC_RELAXED, __HIP_MEMORY_SCOPE_AGENT);
      if (!__any((int)(v < target))) break;
      __builtin_amdgcn_s_sleep(1);
    }
  }
  __syncthreads();
}

// --------------------------------------------------------------- gru ----
// 32 WGs x 512 threads: blockIdx>>4 = dir, &15 = column-slice g.
// WG g owns r cols [g*32,+32), u cols [512+g*32,+32), cand cols [g*32,+32).
// Per phase: stage the shared operand (H[t] / RH[t]) ONCE into LDS via 8B
// coherent loads; MFMA reads LDS; results transposed in LDS then burst out
// as 512 coalesced dword wt-stores.
__global__ __launch_bounds__(512, 1)
void gru_kernel(const float* __restrict__ Wg_fw, const float* __restrict__ Wc_fw,
                const float* __restrict__ Wg_bw, const float* __restrict__ Wc_bw,
                const unsigned short* __restrict__ GX, const unsigned short* __restrict__ GC,
                unsigned short* __restrict__ HFW, unsigned short* __restrict__ HBW,
                unsigned short* __restrict__ RH, unsigned* __restrict__ sync)
{
  __shared__ __align__(16) unsigned short wg_lds[4][16][512];  // 64KB gate B-frags
  __shared__ __align__(16) unsigned short wc_lds[2][16][512];  // 32KB cand B-frags
  __shared__ __align__(16) unsigned short Asm[32][520];        // 33.3KB staged A (padded)
  __shared__ unsigned short hpsm[32][32];                      // 2KB h_prev own-cols
  __shared__ unsigned short rhsm[32][32];                      // 2KB r*h out-stage
  __shared__ unsigned short hnsm[32][32];                      // 2KB h_new out-stage
  __shared__ float u_lds[32][32];                              // 4KB u gate
  __shared__ float red_lds[4][256];                            // 4KB K-split reduce

  const int dir = blockIdx.x >> 4;
  const int g   = blockIdx.x & 15;
  const int tid = threadIdx.x;
  const int wave = tid >> 6, lane = tid & 63;
  const int quad = lane >> 4, l16 = lane & 15;

  const float* Wg = dir ? Wg_bw : Wg_fw;
  const float* Wc = dir ? Wc_bw : Wc_fw;
  unsigned short* H = dir ? HBW : HFW;                 // [S][B][HID]
  unsigned short* RHd = RH + (size_t)dir*S_*B_*HID_;   // [S][B][HID]
  const unsigned short* GXd = GX + (size_t)dir*16384*NGATE;
  const unsigned short* GCd = GC + (size_t)dir*16384*HID_;
  unsigned* fA = sync + dir*1024;
  unsigned* fB = sync + dir*1024 + 512;

  // ---- stage weight h-rows (256..767) into LDS as B-fragments ----
  for (int idx = tid; idx < 4*16*64; idx += 512) {
    int lane_ = idx & 63, kk = (idx >> 6) & 15, nt = idx >> 10;
    int l16_ = lane_ & 15;
    int n = (nt < 2) ? (g*32 + nt*16 + l16_) : (512 + g*32 + (nt-2)*16 + l16_);
    int kb = IN_ + kk*32 + (lane_ >> 4)*8;
    #pragma unroll
    for (int j = 0; j < 8; ++j)
      wg_lds[nt][kk][lane_*8 + j] = f2bf(Wg[(size_t)(kb + j)*NGATE + n]);
  }
  for (int idx = tid; idx < 2*16*64; idx += 512) {
    int lane_ = idx & 63, kk = (idx >> 6) & 15, nt = idx >> 10;
    int n  = g*32 + nt*16 + (lane_ & 15);
    int kb = IN_ + kk*32 + (lane_ >> 4)*8;
    #pragma unroll
    for (int j = 0; j < 8; ++j)
      wc_lds[nt][kk][lane_*8 + j] = f2bf(Wc[(size_t)(kb + j)*HID_ + n]);
  }
  __syncthreads();

  const int amt = wave >> 2, ant = wave & 3;          // phase A: 2mt x 4nt
  const int bmt = wave & 1, bnt = (wave >> 1) & 1;    // phase B: 2mt x 2nt x 2kh
  const int kh  = wave >> 2;

  for (int si = 0; si < S_; ++si) {
    const int t  = dir ? (S_-1-si) : si;
    const int to = dir ? (t-1)     : (t+1);

    wait_flags(fB, (unsigned)si);           // previous step's h fully posted

    // ---- stage Asm <- H[t] (coherent, once per WG): 32 rows x 512 cols ----
    {
      const ull* src = (const ull*)(H + (size_t)t*B_*HID_);   // 4096 u64
      #pragma unroll
      for (int it = 0; it < 8; ++it) {
        int idx = tid + it*512;
        int row = idx >> 7, d = idx & 127;      // row-stride 128 u64 = 512 bf16
        ull v = load_u64_coh(src + row*128 + d);
        *(ull*)&Asm[row][d*4] = v;
      }
    }
    __syncthreads();

    // ======== phase A: gates = sigmoid(h_prev @ Wg_h + GX[t]) ========
    {
      const int b0 = amt*16 + quad*4;
      const int colg = (ant < 2) ? (g*32 + ant*16 + l16)
                                 : (512 + g*32 + (ant-2)*16 + l16);
      const unsigned short* gx = GXd + (size_t)t*B_*NGATE;
      float gxv[4];
      #pragma unroll
      for (int r = 0; r < 4; ++r) gxv[r] = bf2f(gx[(size_t)(b0 + r)*NGATE + colg]);
      f32x4 a0 = {0.f,0.f,0.f,0.f}, a1 = {0.f,0.f,0.f,0.f};
      #pragma unroll
      for (int kk = 0; kk < 16; ++kk) {
        bf16x8 af = *(const bf16x8*)(&Asm[amt*16 + l16][quad*8 + kk*32]);
        bf16x8 bv = *(const bf16x8*)(&wg_lds[ant][kk][lane*8]);
        if (kk & 1) a1 = __builtin_amdgcn_mfma_f32_16x16x32_bf16(af, bv, a1, 0, 0, 0);
        else        a0 = __builtin_amdgcn_mfma_f32_16x16x32_bf16(af, bv, a0, 0, 0, 0);
      }
      f32x4 acc = a0 + a1;
      if (ant < 2) {
        #pragma unroll
        for (int r = 0; r < 4; ++r) {
          float rv = 1.f / (1.f + __expf(-(acc[r] + gxv[r])));
          float hp = bf2f(Asm[b0 + r][colg]);
          rhsm[b0 + r][ant*16 + l16] = f2bf(rv * hp);
        }
      } else {
        #pragma unroll
        for (int r = 0; r < 4; ++r)
          u_lds[b0 + r][(ant-2)*16 + l16] = 1.f / (1.f + __expf(-(acc[r] + gxv[r])));
      }
    }
    // save own-col h_prev slice before Asm gets overwritten by RH staging
    {
      int row = tid >> 4, c2 = (tid & 15)*2;
      *(unsigned*)&hpsm[row][c2] = *(unsigned*)&Asm[row][g*32 + c2];
    }
    __syncthreads();
    // ---- burst rh out (coalesced dword wt-stores) ----
    {
      int row = tid >> 4, c2 = (tid & 15)*2;
      unsigned v = *(unsigned*)&rhsm[row][c2];
      store_dword_wt((unsigned*)(RHd + (size_t)t*B_*HID_ + (size_t)row*HID_ + g*32 + c2), v);
    }
    post_flag(fA, g, (unsigned)(si + 1));
    wait_flags(fA, (unsigned)(si + 1));

    // ---- stage Asm <- RH[t] (coherent, once per WG): 32 rows x 512 cols ----
    {
      const ull* src = (const ull*)(RHd + (size_t)t*B_*HID_);
      #pragma unroll
      for (int it = 0; it < 8; ++it) {
        int idx = tid + it*512;
        int row = idx >> 7, d = idx & 127;
        ull v = load_u64_coh(src + row*128 + d);
        *(ull*)&Asm[row][d*4] = v;
      }
    }
    __syncthreads();

    // ======== phase B: c = tanh(rh @ Wc_h + GC[t]); h update ========
    {
      f32x4 a0 = {0.f,0.f,0.f,0.f}, a1 = {0.f,0.f,0.f,0.f};
      #pragma unroll
      for (int kk = 0; kk < 8; ++kk) {
        bf16x8 af = *(const bf16x8*)(&Asm[bmt*16 + l16][kh*256 + quad*8 + kk*32]);
        bf16x8 bv = *(const bf16x8*)(&wc_lds[bnt][kh*8 + kk][lane*8]);
        if (kk & 1) a1 = __builtin_amdgcn_mfma_f32_16x16x32_bf16(af, bv, a1, 0, 0, 0);
        else        a0 = __builtin_amdgcn_mfma_f32_16x16x32_bf16(af, bv, a0, 0, 0, 0);
      }
      f32x4 acc = a0 + a1;
      const int b0 = bmt*16 + quad*4;
      if (kh) {
        #pragma unroll
        for (int r = 0; r < 4; ++r) red_lds[bmt*2 + bnt][lane*4 + r] = acc[r];
      }
      __syncthreads();
      if (!kh) {
        const int colL = bnt*16 + l16;
        const int colg2 = g*32 + colL;
        #pragma unroll
        for (int r = 0; r < 4; ++r) {
          float sum = acc[r] + red_lds[bmt*2 + bnt][lane*4 + r];
          float gcv = bf2f(GCd[((size_t)t*B_ + b0 + r)*HID_ + colg2]);
          float c   = tanhf(sum + gcv);
          float u   = u_lds[b0 + r][colL];
          float hp  = bf2f(hpsm[b0 + r][colL]);
          hnsm[b0 + r][colL] = f2bf(u * hp + (1.f - u)*c);
        }
      }
    }
    __syncthreads();
    if (to >= 0 && to < S_) {
      int row = tid >> 4, c2 = (tid & 15)*2;
      unsigned v = *(unsigned*)&hnsm[row][c2];
      store_dword_wt((unsigned*)(H + (size_t)to*B_*HID_ + (size_t)row*HID_ + g*32 + c2), v);
    }
    post_flag(fB, g, (unsigned)(si + 1));
  }
}

// ---------------------------------------------------------------- fc ----
// last[b][t] = [HFW[t] | Xbf[t] | HBW[t]]; pool = max_t relu(last@fcw+fcb)
__global__ __launch_bounds__(512, 1)
void fc_kernel(const unsigned short* __restrict__ HFW, const unsigned short* __restrict__ HBW,
               const unsigned short* __restrict__ Xbf,
               const unsigned short* __restrict__ fcwf, const float* __restrict__ fcb,
               float* __restrict__ pool)
{
  __shared__ unsigned short bsm[32*512];   // 32KB weight chunk (frag order)
  __shared__ float red[8*512];             // 16KB cross-wave max reduce
  const int wg = blockIdx.x;               // 128 WGs: b = wg/4, t-quarter = wg%4
  const int b  = wg >> 2;
  const int tid = threadIdx.x, wave = tid >> 6, lane = tid & 63;
  const int quad = lane >> 4, l16 = lane & 15;
  const int t = (wg & 3)*128 + wave*16 + l16;  // A-operand row = t

  f32x4 acc[32];
  #pragma unroll
  for (int nt = 0; nt < 32; ++nt) acc[nt] = (f32x4){0.f,0.f,0.f,0.f};

  for (int kc = 0; kc < 40; ++kc) {
    __syncthreads();
    const uint4* src = (const uint4*)(fcwf + (size_t)kc*32*512);
    uint4* dst = (uint4*)bsm;
    #pragma unroll
    for (int r = 0; r < 4; ++r) dst[tid + r*512] = src[tid + r*512];
    __syncthreads();

    const unsigned short* ap;
    if (kc < 16)      ap = HFW + ((size_t)t*B_ + b)*HID_ + kc*32 + quad*8;        // c_left
    else if (kc < 24) ap = Xbf + ((size_t)t*B_ + b)*IN_ + (kc - 16)*32 + quad*8;  // x
    else              ap = HBW + ((size_t)t*B_ + b)*HID_ + (kc - 24)*32 + quad*8; // c_right
    const bf16x8 af = *(const bf16x8*)ap;
    #pragma unroll
    for (int nt = 0; nt < 32; ++nt) {
      bf16x8 bfv = *(const bf16x8*)(&bsm[(nt*64 + lane)*8]);
      acc[nt] = __builtin_amdgcn_mfma_f32_16x16x32_bf16(af, bfv, acc[nt], 0, 0, 0);
    }
  }
  #pragma unroll
  for (int nt = 0; nt < 32; ++nt) {
    float m = fmaxf(fmaxf(acc[nt][0], acc[nt][1]), fmaxf(acc[nt][2], acc[nt][3]));
    m = fmaxf(m, __shfl_xor(m, 16, 64));
    m = fmaxf(m, __shfl_xor(m, 32, 64));
    if (quad == 0) red[wave*512 + nt*16 + l16] = m;
  }
  __syncthreads();
  {
    float m = red[tid];
    #pragma unroll
    for (int w = 1; w < 8; ++w) m = fmaxf(m, red[w*512 + tid]);
    m = fmaxf(m + fcb[tid], 0.f);
    atomicMax((int*)&pool[(size_t)b*HID_ + tid], __float_as_int(m));
  }
}

// --------------------------------------------------------------- mlp ----
__global__ void mlp_kernel(const float* __restrict__ pool, const float* __restrict__ w,
                           const float* __restrict__ bias, float* __restrict__ out)
{
  __shared__ float p[HID_];
  const int b = blockIdx.x, tid = threadIdx.x;  // 256 threads
  p[tid]       = pool[(size_t)b*HID_ + tid];
  p[tid + 256] = pool[(size_t)b*HID_ + 256 + tid];
  __syncthreads();
  float acc = bias[tid];
  for (int k = 0; k < HID_; ++k) acc += p[k] * w[(size_t)k*OUT_ + tid];
  out[(size_t)b*OUT_ + tid] = acc;
}

// ------------------------------------------------------------ launch ----
extern "C" void kernel_launch(void* const* d_in, const int* in_sizes, int n_in,
                              void* d_out, int out_size, void* d_ws, size_t ws_size,
                              hipStream_t stream)
{
  const float* x    = (const float*)d_in[0];
  const float* fwWg = (const float*)d_in[1];
  const float* fwbg = (const float*)d_in[2];
  const float* fwWc = (const float*)d_in[3];
  const float* fwbc = (const float*)d_in[4];
  const float* bwWg = (const float*)d_in[5];
  const float* bwbg = (const float*)d_in[6];
  const float* bwWc = (const float*)d_in[7];
  const float* bwbc = (const float*)d_in[8];
  const float* fcw  = (const float*)d_in[9];
  const float* fcb  = (const float*)d_in[10];
  const float* mlpw = (const float*)d_in[11];
  const float* mlpb = (const float*)d_in[12];
  float* out = (float*)d_out;

  char* p = (char*)d_ws;
  auto take = [&](size_t bytes) { char* r = p; p += (bytes + 255) & ~size_t(255); return r; };
  unsigned short* Xbf  = (unsigned short*)take((size_t)S_*B_*IN_*2);          // 8MB
  unsigned short* HFW  = (unsigned short*)take((size_t)S_*B_*HID_*2);         // 16.8MB
  unsigned short* HBW  = (unsigned short*)take((size_t)S_*B_*HID_*2);         // 16.8MB
  unsigned short* GX   = (unsigned short*)take((size_t)2*S_*B_*NGATE*2);      // 67MB
  unsigned short* GC   = (unsigned short*)take((size_t)2*S_*B_*HID_*2);       // 33.6MB
  unsigned short* RH   = (unsigned short*)take((size_t)2*S_*B_*HID_*2);       // 33.6MB
  unsigned short* fcwf = (unsigned short*)take((size_t)40*32*64*8*2);         // 1.25MB
  float*          pool = (float*)take((size_t)B_*HID_*4);
  unsigned*       sync = (unsigned*)take(8192);   // 2048 dwords of flags

  prep_kernel<<<2048, 256, 0, stream>>>(x, fcw, Xbf, HFW, HBW, pool, sync, fcwf);
  pregemm_kernel<<<12288, 256, 0, stream>>>(Xbf, fwWg, fwbg, fwWc, fwbc,
                                            bwWg, bwbg, bwWc, bwbc, GX, GC);
  gru_kernel<<<2*NWGD, 512, 0, stream>>>(fwWg, fwWc, bwWg, bwWc,
                                         GX, GC, HFW, HBW, RH, sync);
  fc_kernel<<<128, 512, 0, stream>>>(HFW, HBW, Xbf, fcwf, fcb, pool);
  mlp_kernel<<<32, 256, 0, stream>>>(pool, mlpw, mlpb, out);
}

// Round 10
// 4714.955 us; speedup vs baseline: 2.1058x; 1.0531x over previous
//
#include <hip/hip_runtime.h>
#include <hip/hip_bf16.h>
#include <cstdint>
#include <cstddef>

#define B_    32
#define S_    512
#define IN_   256
#define HID_  512
#define NGATE 1024
#define OUT_  256
#define NWGD  16         // worker WGs per direction (each owns 32 r/u/cand cols)

typedef float f32x4 __attribute__((ext_vector_type(4)));
typedef short bf16x8 __attribute__((ext_vector_type(8)));
typedef unsigned long long ull;

__device__ inline unsigned short f2bf(float f) {
  return __builtin_bit_cast(unsigned short, __float2bfloat16(f));
}
__device__ inline float bf2f(unsigned short u) {
  union { float f; unsigned int i; } v; v.i = ((unsigned int)u) << 16; return v.f;
}

// write-through stores: bypass L1/L2 dirty state, land at IF$ (device
// coherent point).  R1/R2/R3/R7-verified.
__device__ inline void store_dword_wt(unsigned* p, unsigned val) {
  asm volatile("global_store_dword %0, %1, off sc0 sc1" :: "v"(p), "v"(val) : "memory");
}
// 64-bit scalar operand -> VGPR pair (struct operands are not supported).
__device__ inline void store_dwordx2_wt(ull* p, ull val) {
  asm volatile("global_store_dwordx2 %0, %1, off sc0 sc1" :: "v"(p), "v"(val) : "memory");
}

// ---------------------------------------------------------------- prep ----
__global__ void prep_kernel(const float* __restrict__ x,
                            const float* __restrict__ fcw,
                            unsigned short* __restrict__ Xbf,
                            unsigned short* __restrict__ HFW,
                            unsigned short* __restrict__ HBW,
                            float* __restrict__ pool,
                            unsigned* __restrict__ sync,
                            unsigned short* __restrict__ fcwf)
{
  const int nthreads = gridDim.x * blockDim.x;
  const int gtid = blockIdx.x * blockDim.x + threadIdx.x;

  // x [B,S,IN] -> Xbf [S][B][IN] bf16
  for (int i = gtid; i < S_*B_*IN_; i += nthreads) {
    int c = i & (IN_-1);
    int rem = i >> 8;
    int b = rem & (B_-1);
    int s = rem >> 5;
    Xbf[((size_t)s*B_ + b)*IN_ + c] = f2bf(x[((size_t)b*S_ + s)*IN_ + c]);
  }
  // HFW[0] = 0 (h_{-1}), HBW[S-1] = 0 (hb_S)
  for (int i = gtid; i < B_*HID_; i += nthreads) {
    HFW[i] = 0;
    HBW[(size_t)(S_-1)*B_*HID_ + i] = 0;
  }
  for (int i = gtid; i < B_*HID_; i += nthreads) pool[i] = 0.f;
  for (int i = gtid; i < 2048;    i += nthreads) sync[i] = 0u;
  // fc_w [1280][512] -> fragment order [kc=40][nt=32][lane=64][8]
  for (int i = gtid; i < 40*32*64*8; i += nthreads) {
    int j     = i & 7;
    int lane_ = (i >> 3) & 63;
    int nt    = (i >> 9) & 31;
    int kc    = i >> 14;
    int k = kc*32 + (lane_ >> 4)*8 + j;
    int n = nt*16 + (lane_ & 15);
    fcwf[i] = f2bf(fcw[(size_t)k*HID_ + n]);
  }
}

// ------------------------------------------------------------- pregemm ----
// GX[dir][t*32+b][1024] = x_{t,b} @ Wg[0:256,:] + bg   (bf16)  [R3-verified]
// GC[dir][t*32+b][512]  = x_{t,b} @ Wc[0:256,:] + bc   (bf16)
__global__ __launch_bounds__(256, 1)
void pregemm_kernel(const unsigned short* __restrict__ Xbf,
                    const float* __restrict__ Wg_fw, const float* __restrict__ bg_fw,
                    const float* __restrict__ Wc_fw, const float* __restrict__ bc_fw,
                    const float* __restrict__ Wg_bw, const float* __restrict__ bg_bw,
                    const float* __restrict__ Wc_bw, const float* __restrict__ bc_bw,
                    unsigned short* __restrict__ GX, unsigned short* __restrict__ GC)
{
  __shared__ unsigned short bsm[4*8*64*8];   // 32KB [nt4][kk8][lane][8]
  const int id  = blockIdx.x;                // 0..12287
  const int dir = id >= 6144;
  const int r0  = id - dir*6144;
  const int mtile = r0 / 24;
  const int sec   = r0 % 24;
  const bool isG  = sec < 16;
  const float* W    = dir ? (isG ? Wg_bw : Wc_bw) : (isG ? Wg_fw : Wc_fw);
  const float* bias = dir ? (isG ? bg_bw : bc_bw) : (isG ? bg_fw : bc_fw);
  const int N     = isG ? NGATE : HID_;
  const int nbase = (isG ? sec : sec - 16) * 64;
  unsigned short* out = isG ? (GX + (size_t)dir*16384*NGATE)
                            : (GC + (size_t)dir*16384*HID_);
  const int m0 = mtile * 64;
  const int tid = threadIdx.x, wave = tid >> 6, lane = tid & 63;
  const int quad = lane >> 4, l16 = lane & 15;

  for (int idx = tid; idx < 4*8*64; idx += 256) {
    int lane_ = idx & 63, kk = (idx >> 6) & 7, nt = idx >> 9;
    int n  = nbase + nt*16 + (lane_ & 15);
    int kb = kk*32 + (lane_ >> 4)*8;
    #pragma unroll
    for (int j = 0; j < 8; ++j)
      bsm[((nt*8 + kk)*64 + lane_)*8 + j] = f2bf(W[(size_t)(kb + j)*N + n]);
  }
  __syncthreads();

  f32x4 acc[4];
  #pragma unroll
  for (int nt = 0; nt < 4; ++nt) acc[nt] = (f32x4){0.f,0.f,0.f,0.f};
  #pragma unroll
  for (int kk = 0; kk < 8; ++kk) {
    bf16x8 af = *(const bf16x8*)(Xbf + (size_t)(m0 + wave*16 + l16)*IN_ + quad*8 + kk*32);
    #pragma unroll
    for (int nt = 0; nt < 4; ++nt) {
      bf16x8 bv = *(const bf16x8*)(&bsm[((nt*8 + kk)*64 + lane)*8]);
      acc[nt] = __builtin_amdgcn_mfma_f32_16x16x32_bf16(af, bv, acc[nt], 0, 0, 0);
    }
  }
  #pragma unroll
  for (int nt = 0; nt < 4; ++nt)
    #pragma unroll
    for (int r = 0; r < 4; ++r) {
      int row = m0 + wave*16 + quad*4 + r;
      int col = nbase + nt*16 + l16;
      out[(size_t)row*N + col] = f2bf(acc[nt][r] + bias[col]);
    }
}

// ----------------------------------------------------------- barrier ----
// Each flag on its own 64B line; polled with agent-relaxed atomic loads.
// __syncthreads inside post_flag drains this WG's wt stores (vmcnt(0))
// before the flag post.  [R1/R2/R3/R7-verified]
__device__ inline void post_flag(unsigned* base, int g, unsigned v) {
  __syncthreads();
  if (threadIdx.x == 0) store_dword_wt(base + g*16, v);
}
__device__ inline void wait_flags(unsigned* base, unsigned target) {
  if (threadIdx.x < 64) {
    const unsigned* p = base + (threadIdx.x & (NWGD-1))*16;
    for (;;) {
      unsigned v = __hip_atomic_load(p, __ATOMIC_RELAXED, __HIP_MEMORY_SCOPE_AGENT);
      if (!__any((int)(v < target))) break;
      __builtin_amdgcn_s_sleep(1);
    }
  }
  __syncthreads();
}

// --------------------------------------------------------------- gru ----
// 32 WGs x 512 threads: blockIdx>>4 = dir, &15 = column-slice g.
// WG g owns r cols [g*32,+32), u cols [512+g*32,+32), cand cols [g*32,+32).
// A-fragments are loaded DIRECTLY from global with plain 16B loads after the
// flag (fresh-after-wt-store, R1-verified); results leave via LDS transpose
// + 256 coalesced dwordx2 wt-stores.
__global__ __launch_bounds__(512, 1)
void gru_kernel(const float* __restrict__ Wg_fw, const float* __restrict__ Wc_fw,
                const float* __restrict__ Wg_bw, const float* __restrict__ Wc_bw,
                const unsigned short* __restrict__ GX, const unsigned short* __restrict__ GC,
                unsigned short* __restrict__ HFW, unsigned short* __restrict__ HBW,
                unsigned short* __restrict__ RH, unsigned* __restrict__ sync)
{
  __shared__ __align__(16) unsigned short wg_lds[4][16][512];  // 64KB gate B-frags
  __shared__ __align__(16) unsigned short wc_lds[2][16][512];  // 32KB cand B-frags
  __shared__ __align__(16) unsigned short rhsm[32][32];        // 2KB r*h out-stage
  __shared__ __align__(16) unsigned short hnsm[32][32];        // 2KB h_new out-stage
  __shared__ float u_lds[32][32];                              // 4KB u gate
  __shared__ float red_lds[4][256];                            // 4KB K-split reduce

  const int dir = blockIdx.x >> 4;
  const int g   = blockIdx.x & 15;
  const int tid = threadIdx.x;
  const int wave = tid >> 6, lane = tid & 63;
  const int quad = lane >> 4, l16 = lane & 15;

  const float* Wg = dir ? Wg_bw : Wg_fw;
  const float* Wc = dir ? Wc_bw : Wc_fw;
  unsigned short* H = dir ? HBW : HFW;                 // [S][B][HID]
  unsigned short* RHd = RH + (size_t)dir*S_*B_*HID_;   // [S][B][HID]
  const unsigned short* GXd = GX + (size_t)dir*16384*NGATE;
  const unsigned short* GCd = GC + (size_t)dir*16384*HID_;
  unsigned* fA = sync + dir*1024;
  unsigned* fB = sync + dir*1024 + 512;

  // ---- stage weight h-rows (256..767) into LDS as B-fragments ----
  for (int idx = tid; idx < 4*16*64; idx += 512) {
    int lane_ = idx & 63, kk = (idx >> 6) & 15, nt = idx >> 10;
    int l16_ = lane_ & 15;
    int n = (nt < 2) ? (g*32 + nt*16 + l16_) : (512 + g*32 + (nt-2)*16 + l16_);
    int kb = IN_ + kk*32 + (lane_ >> 4)*8;
    #pragma unroll
    for (int j = 0; j < 8; ++j)
      wg_lds[nt][kk][lane_*8 + j] = f2bf(Wg[(size_t)(kb + j)*NGATE + n]);
  }
  for (int idx = tid; idx < 2*16*64; idx += 512) {
    int lane_ = idx & 63, kk = (idx >> 6) & 15, nt = idx >> 10;
    int n  = g*32 + nt*16 + (lane_ & 15);
    int kb = IN_ + kk*32 + (lane_ >> 4)*8;
    #pragma unroll
    for (int j = 0; j < 8; ++j)
      wc_lds[nt][kk][lane_*8 + j] = f2bf(Wc[(size_t)(kb + j)*HID_ + n]);
  }
  __syncthreads();

  const int amt = wave >> 2, ant = wave & 3;          // phase A: 2mt x 4nt
  const int bmt = wave & 1, bnt = (wave >> 1) & 1;    // phase B: 2mt x 2nt x 2kh
  const int kh  = wave >> 2;
  const int b0A = amt*16 + quad*4;
  const int b0B = bmt*16 + quad*4;
  const int colB = g*32 + bnt*16 + l16;               // phase B output col

  for (int si = 0; si < S_; ++si) {
    const int t  = dir ? (S_-1-si) : si;
    const int to = dir ? (t-1)     : (t+1);
    const unsigned short* Ht = H + (size_t)t*B_*HID_;

    wait_flags(fB, (unsigned)si);           // h_prev (H[t]) fully posted

    // ======== phase A: gates = sigmoid(h_prev @ Wg_h + GX[t]) ========
    float gcv[4], hpB[4];                   // phase-B prefetch (indep of rh)
    {
      const int colg = (ant < 2) ? (g*32 + ant*16 + l16)
                                 : (512 + g*32 + (ant-2)*16 + l16);
      const unsigned short* gx = GXd + (size_t)t*B_*NGATE;
      float gxv[4];
      #pragma unroll
      for (int r = 0; r < 4; ++r) gxv[r] = bf2f(gx[(size_t)(b0A + r)*NGATE + colg]);
      float hpA[4];
      if (ant < 2) {
        #pragma unroll
        for (int r = 0; r < 4; ++r) hpA[r] = bf2f(Ht[(size_t)(b0A + r)*HID_ + colg]);
      }
      // phase-B operand prefetch (kh==0 waves consume them after fA)
      if (kh == 0) {
        #pragma unroll
        for (int r = 0; r < 4; ++r) {
          gcv[r] = bf2f(GCd[((size_t)t*B_ + b0B + r)*HID_ + colB]);
          hpB[r] = bf2f(Ht[(size_t)(b0B + r)*HID_ + colB]);
        }
      }
      // direct 16B A-frag loads (fresh-after-flag)
      const unsigned short* arow = Ht + (size_t)(amt*16 + l16)*HID_ + quad*8;
      f32x4 a0 = {0.f,0.f,0.f,0.f}, a1 = {0.f,0.f,0.f,0.f};
      #pragma unroll
      for (int kk = 0; kk < 16; ++kk) {
        bf16x8 af = *(const bf16x8*)(arow + kk*32);
        bf16x8 bv = *(const bf16x8*)(&wg_lds[ant][kk][lane*8]);
        if (kk & 1) a1 = __builtin_amdgcn_mfma_f32_16x16x32_bf16(af, bv, a1, 0, 0, 0);
        else        a0 = __builtin_amdgcn_mfma_f32_16x16x32_bf16(af, bv, a0, 0, 0, 0);
      }
      f32x4 acc = a0 + a1;
      if (ant < 2) {
        #pragma unroll
        for (int r = 0; r < 4; ++r) {
          float rv = 1.f / (1.f + __expf(-(acc[r] + gxv[r])));
          rhsm[b0A + r][ant*16 + l16] = f2bf(rv * hpA[r]);
        }
      } else {
        #pragma unroll
        for (int r = 0; r < 4; ++r)
          u_lds[b0A + r][(ant-2)*16 + l16] = 1.f / (1.f + __expf(-(acc[r] + gxv[r])));
      }
    }
    __syncthreads();
    // ---- burst rh out: 256 x dwordx2 wt-stores ----
    if (tid < 256) {
      int row = tid >> 3, c4 = (tid & 7)*4;
      ull v = *(const ull*)&rhsm[row][c4];
      store_dwordx2_wt((ull*)(RHd + (size_t)t*B_*HID_ + (size_t)row*HID_ + g*32 + c4), v);
    }
    post_flag(fA, g, (unsigned)(si + 1));
    wait_flags(fA, (unsigned)(si + 1));

    // ======== phase B: c = tanh(rh @ Wc_h + GC[t]); h update ========
    {
      const unsigned short* rrow = RHd + (size_t)t*B_*HID_
                                 + (size_t)(bmt*16 + l16)*HID_ + kh*256 + quad*8;
      f32x4 a0 = {0.f,0.f,0.f,0.f}, a1 = {0.f,0.f,0.f,0.f};
      #pragma unroll
      for (int kk = 0; kk < 8; ++kk) {
        bf16x8 af = *(const bf16x8*)(rrow + kk*32);
        bf16x8 bv = *(const bf16x8*)(&wc_lds[bnt][kh*8 + kk][lane*8]);
        if (kk & 1) a1 = __builtin_amdgcn_mfma_f32_16x16x32_bf16(af, bv, a1, 0, 0, 0);
        else        a0 = __builtin_amdgcn_mfma_f32_16x16x32_bf16(af, bv, a0, 0, 0, 0);
      }
      f32x4 acc = a0 + a1;
      if (kh) {
        #pragma unroll
        for (int r = 0; r < 4; ++r) red_lds[bmt*2 + bnt][lane*4 + r] = acc[r];
      }
      __syncthreads();
      if (!kh) {
        #pragma unroll
        for (int r = 0; r < 4; ++r) {
          float sum = acc[r] + red_lds[bmt*2 + bnt][lane*4 + r];
          float c   = tanhf(sum + gcv[r]);
          float u   = u_lds[b0B + r][bnt*16 + l16];
          hnsm[b0B + r][bnt*16 + l16] = f2bf(u * hpB[r] + (1.f - u)*c);
        }
      }
    }
    __syncthreads();
    if (to >= 0 && to < S_ && tid < 256) {
      int row = tid >> 3, c4 = (tid & 7)*4;
      ull v = *(const ull*)&hnsm[row][c4];
      store_dwordx2_wt((ull*)(H + (size_t)to*B_*HID_ + (size_t)row*HID_ + g*32 + c4), v);
    }
    post_flag(fB, g, (unsigned)(si + 1));
  }
}

// ---------------------------------------------------------------- fc ----
// last[b][t] = [HFW[t] | Xbf[t] | HBW[t]]; pool = max_t relu(last@fcw+fcb)
__global__ __launch_bounds__(512, 1)
void fc_kernel(const unsigned short* __restrict__ HFW, const unsigned short* __restrict__ HBW,
               const unsigned short* __restrict__ Xbf,
               const unsigned short* __restrict__ fcwf, const float* __restrict__ fcb,
               float* __restrict__ pool)
{
  __shared__ unsigned short bsm[32*512];   // 32KB weight chunk (frag order)
  __shared__ float red[8*512];             // 16KB cross-wave max reduce
  const int wg = blockIdx.x;               // 128 WGs: b = wg/4, t-quarter = wg%4
  const int b  = wg >> 2;
  const int tid = threadIdx.x, wave = tid >> 6, lane = tid & 63;
  const int quad = lane >> 4, l16 = lane & 15;
  const int t = (wg & 3)*128 + wave*16 + l16;  // A-operand row = t

  f32x4 acc[32];
  #pragma unroll
  for (int nt = 0; nt < 32; ++nt) acc[nt] = (f32x4){0.f,0.f,0.f,0.f};

  for (int kc = 0; kc < 40; ++kc) {
    __syncthreads();
    const uint4* src = (const uint4*)(fcwf + (size_t)kc*32*512);
    uint4* dst = (uint4*)bsm;
    #pragma unroll
    for (int r = 0; r < 4; ++r) dst[tid + r*512] = src[tid + r*512];
    __syncthreads();

    const unsigned short* ap;
    if (kc < 16)      ap = HFW + ((size_t)t*B_ + b)*HID_ + kc*32 + quad*8;        // c_left
    else if (kc < 24) ap = Xbf + ((size_t)t*B_ + b)*IN_ + (kc - 16)*32 + quad*8;  // x
    else              ap = HBW + ((size_t)t*B_ + b)*HID_ + (kc - 24)*32 + quad*8; // c_right
    const bf16x8 af = *(const bf16x8*)ap;
    #pragma unroll
    for (int nt = 0; nt < 32; ++nt) {
      bf16x8 bfv = *(const bf16x8*)(&bsm[(nt*64 + lane)*8]);
      acc[nt] = __builtin_amdgcn_mfma_f32_16x16x32_bf16(af, bfv, acc[nt], 0, 0, 0);
    }
  }
  #pragma unroll
  for (int nt = 0; nt < 32; ++nt) {
    float m = fmaxf(fmaxf(acc[nt][0], acc[nt][1]), fmaxf(acc[nt][2], acc[nt][3]));
    m = fmaxf(m, __shfl_xor(m, 16, 64));
    m = fmaxf(m, __shfl_xor(m, 32, 64));
    if (quad == 0) red[wave*512 + nt*16 + l16] = m;
  }
  __syncthreads();
  {
    float m = red[tid];
    #pragma unroll
    for (int w = 1; w < 8; ++w) m = fmaxf(m, red[w*512 + tid]);
    m = fmaxf(m + fcb[tid], 0.f);
    atomicMax((int*)&pool[(size_t)b*HID_ + tid], __float_as_int(m));
  }
}

// --------------------------------------------------------------- mlp ----
__global__ void mlp_kernel(const float* __restrict__ pool, const float* __restrict__ w,
                           const float* __restrict__ bias, float* __restrict__ out)
{
  __shared__ float p[HID_];
  const int b = blockIdx.x, tid = threadIdx.x;  // 256 threads
  p[tid]       = pool[(size_t)b*HID_ + tid];
  p[tid + 256] = pool[(size_t)b*HID_ + 256 + tid];
  __syncthreads();
  float acc = bias[tid];
  for (int k = 0; k < HID_; ++k) acc += p[k] * w[(size_t)k*OUT_ + tid];
  out[(size_t)b*OUT_ + tid] = acc;
}

// ------------------------------------------------------------ launch ----
extern "C" void kernel_launch(void* const* d_in, const int* in_sizes, int n_in,
                              void* d_out, int out_size, void* d_ws, size_t ws_size,
                              hipStream_t stream)
{
  const float* x    = (const float*)d_in[0];
  const float* fwWg = (const float*)d_in[1];
  const float* fwbg = (const float*)d_in[2];
  const float* fwWc = (const float*)d_in[3];
  const float* fwbc = (const float*)d_in[4];
  const float* bwWg = (const float*)d_in[5];
  const float* bwbg = (const float*)d_in[6];
  const float* bwWc = (const float*)d_in[7];
  const float* bwbc = (const float*)d_in[8];
  const float* fcw  = (const float*)d_in[9];
  const float* fcb  = (const float*)d_in[10];
  const float* mlpw = (const float*)d_in[11];
  const float* mlpb = (const float*)d_in[12];
  float* out = (float*)d_out;

  char* p = (char*)d_ws;
  auto take = [&](size_t bytes) { char* r = p; p += (bytes + 255) & ~size_t(255); return r; };
  unsigned short* Xbf  = (unsigned short*)take((size_t)S_*B_*IN_*2);          // 8MB
  unsigned short* HFW  = (unsigned short*)take((size_t)S_*B_*HID_*2);         // 16.8MB
  unsigned short* HBW  = (unsigned short*)take((size_t)S_*B_*HID_*2);         // 16.8MB
  unsigned short* GX   = (unsigned short*)take((size_t)2*S_*B_*NGATE*2);      // 67MB
  unsigned short* GC   = (unsigned short*)take((size_t)2*S_*B_*HID_*2);       // 33.6MB
  unsigned short* RH   = (unsigned short*)take((size_t)2*S_*B_*HID_*2);       // 33.6MB
  unsigned short* fcwf = (unsigned short*)take((size_t)40*32*64*8*2);         // 1.25MB
  float*          pool = (float*)take((size_t)B_*HID_*4);
  unsigned*       sync = (unsigned*)take(8192);   // 2048 dwords of flags

  prep_kernel<<<2048, 256, 0, stream>>>(x, fcw, Xbf, HFW, HBW, pool, sync, fcwf);
  pregemm_kernel<<<12288, 256, 0, stream>>>(Xbf, fwWg, fwbg, fwWc, fwbc,
                                            bwWg, bwbg, bwWc, bwbc, GX, GC);
  gru_kernel<<<2*NWGD, 512, 0, stream>>>(fwWg, fwWc, bwWg, bwWc,
                                         GX, GC, HFW, HBW, RH, sync);
  fc_kernel<<<128, 512, 0, stream>>>(HFW, HBW, Xbf, fcwf, fcb, pool);
  mlp_kernel<<<32, 256, 0, stream>>>(pool, mlpw, mlpb, out);
}